// Round 14
// baseline (72.363 us; speedup 1.0000x reference)
//
#include <hip/hip_runtime.h>
#include <math.h>

// BoundaryDistanceLoss — H=W=1024 binary masks (float 0/1).
// edges = seg - erode3x3(seg); exact EDT of edges; loss =
// sigmoid((mean(target_edges*pred_dt) + mean(pred_edges*target_dt))/2).
//
// R13->R14: k_main is latency-bound (~20us vs ~2us VALU). (1) RPB 128->64:
// 2048 blocks = 8/CU = 32 waves/CU (max occupancy), per-thread EDT halved.
// (2) staging sbytes round-trip replaced by register packing: 8 lanes/row,
// coalesced float4 loads, nibble in-register, 3x shfl_xor OR -> lane0 stores
// the u32 row mask. One fewer syncthreads, -2.2KB LDS. Math identical to
// R13 (absmax 0.0): 16-col tile, 32-col window, exact iff
// D2 <= min(64, dl^2, dr^2), dead global fallback. 2 nodes, no atomics.
//
// ws layout: partial (8KB f32) only.

#define HW 1024
#define WIN 8
#define RPB 64
#define KROWS (RPB + 2 * WIN)   // 80
#define HS_STRIDE 17
#define NC (RPB + 18)           // 82 segc rows: [i0-9, i0+73)
#define NW (RPB + 2)            // 66 segw rows: [i0-1, i0+65)
#define NROWS (NC + NW)         // 148
#define NSLOT (NROWS * 8)       // 1184 lane-slots (8 chunks/row)

// edge test straight from global seg (fallback only; zero-pad semantics)
__device__ inline int edge_at(const float* __restrict__ seg, int k, int j)
{
    if ((unsigned)k >= (unsigned)HW || (unsigned)j >= (unsigned)HW) return 0;
    if (seg[k * HW + j] == 0.f) return 0;
    bool all9 = true;
    #pragma unroll
    for (int dy = -1; dy <= 1; ++dy)
        #pragma unroll
        for (int dx = -1; dx <= 1; ++dx) {
            const int kk = k + dy, jj = j + dx;
            const float v = ((unsigned)kk < (unsigned)HW && (unsigned)jj < (unsigned)HW)
                            ? seg[kk * HW + jj] : 0.f;
            all9 = all9 && (v != 0.f);
        }
    return all9 ? 0 : 1;
}

// ------------- Fused kernel: windowed row-pass + column EDT + partial -------
// grid (64 col-tiles, 16 row-chunks, 2 images) = 2048 blocks, block 256.
__global__ __launch_bounds__(256)
void k_main(const float* __restrict__ pred, const float* __restrict__ targ,
            float* __restrict__ partial)
{
    const int t  = threadIdx.x;
    const int j0 = blockIdx.x * 16;
    const int i0 = blockIdx.y * RPB;
    const int mc = blockIdx.z;
    const float* __restrict__ segc = mc ? targ : pred;   // image whose DT we take
    const float* __restrict__ segw = mc ? pred : targ;   // OTHER image (weights)

    __shared__ unsigned s_m[NROWS];          // u32 row masks (segc then segw)
    __shared__ float hs[KROWS * HS_STRIDE];
    __shared__ unsigned short esb[RPB];
    __shared__ float wsum[4];

    // 32-col window: cols [W0, W0+32); tile at bits 8..23.
    // W0 = 16*bx - 8 is a multiple of 4 -> float4 chunks 16B-aligned and
    // never straddle the image border.
    const int W0 = j0 - 8;

    // Phase 1: stage window bits — 8 lanes per row, coalesced float4 loads,
    // in-register nibble, 3-step shfl_xor OR combine, lane0-of-8 stores mask.
    #pragma unroll
    for (int it = 0; it < 5; ++it) {
        const int idx = t + it * 256;
        unsigned partm = 0;
        int row = -1;
        if (idx < NSLOT) {
            row = idx >> 3;
            const int c4 = idx & 7;
            const int isW = row >= NC;
            const int gr  = isW ? (i0 - 1 + (row - NC)) : (i0 - 9 + row);
            const int c   = W0 + c4 * 4;
            float4 v = make_float4(0.f, 0.f, 0.f, 0.f);
            if ((unsigned)gr < (unsigned)HW && (unsigned)c <= 1020u) {
                const float* __restrict__ base = isW ? segw : segc;
                v = *(const float4*)&base[gr * HW + c];
            }
            const unsigned by = (unsigned)(v.x != 0.f) | ((unsigned)(v.y != 0.f) << 1)
                              | ((unsigned)(v.z != 0.f) << 2) | ((unsigned)(v.w != 0.f) << 3);
            partm = by << (4 * c4);
        }
        partm |= __shfl_xor(partm, 1);
        partm |= __shfl_xor(partm, 2);
        partm |= __shfl_xor(partm, 4);
        if (idx < NSLOT && (t & 7) == 0) s_m[row] = partm;
    }
    __syncthreads();

    // Phase 2a: weight edge words (other image), rows [i0, i0+64)
    if (t < RPB) {
        const unsigned sA = s_m[NC + t], sB = s_m[NC + t + 1], sC = s_m[NC + t + 2];
        const unsigned va = sA & sB & sC;
        const unsigned er = va & (va << 1) & (va >> 1);
        const unsigned edge = sB & ~er;          // tile bits 8..23 have valid nbrs
        esb[t] = (unsigned short)((edge >> 8) & 0xFFFFu);
    }
    // Phase 2b: windowed row-pass -> h = g^2 + kr^2 (threads 0..79, u32 ops)
    if (t < KROWS) {
        const int kr = i0 - WIN + t;             // edge row for hs row t
        float* __restrict__ hrow = &hs[t * HS_STRIDE];
        if ((unsigned)kr < (unsigned)HW) {
            const unsigned sA = s_m[t], sB = s_m[t + 1], sC = s_m[t + 2];
            const unsigned va = sA & sB & sC;
            const unsigned er = va & (va << 1) & (va >> 1);
            // bits 0/31 lack a col-neighbor: excluded as edge candidates; any
            // such miss is >=8 cols from the tile -> covered by the 64 check
            const unsigned edge = (sB & ~er) & 0x7FFFFFFEu;
            const float krk = (float)(kr * kr);
            #pragma unroll
            for (int jc = 0; jc < 16; ++jc) {
                const int p = 8 + jc;            // p in [8,24)
                const unsigned mle = edge & ((1u << (p + 1)) - 1u);
                const unsigned mge = edge >> p;
                int g = 1 << 20;
                if (mle) g = p - (31 - __clz(mle));
                if (mge) g = min(g, __ffs(mge) - 1);
                hrow[jc] = (g < (1 << 20)) ? fmaf((float)g, (float)g, krk) : 1e30f;
            }
        } else {
            #pragma unroll
            for (int jc = 0; jc < 16; ++jc) hrow[jc] = 1e30f;
        }
    }
    __syncthreads();

    // Phase 3: column EDT (windowed, exact) + weighted sum
    const int jj = t & 15;
    const int iw = t >> 4;                       // 0..15, each owns 4 rows
    float lsum = 0.f;
    {
        const int ib = i0 + iw * 4;              // 4 consecutive output rows
        const int kkS = iw * 4;                  // = (ib-WIN) - (i0-WIN)
        float b0 = 3e38f, b1 = 3e38f, b2 = 3e38f, b3 = 3e38f;
        float kf = (float)(ib - WIN);
        const float m0 = -2.f * (float)(ib);
        const float m1 = -2.f * (float)(ib + 1);
        const float m2 = -2.f * (float)(ib + 2);
        const float m3 = -2.f * (float)(ib + 3);
        #pragma unroll
        for (int kk = kkS; kk < kkS + 2 * WIN + 4; ++kk) {
            const float hvv = hs[kk * HS_STRIDE + jj];
            b0 = fminf(b0, fmaf(m0, kf, hvv));
            b1 = fminf(b1, fmaf(m1, kf, hvv));
            b2 = fminf(b2, fmaf(m2, kf, hvv));
            b3 = fminf(b3, fmaf(m3, kf, hvv));
            kf += 1.f;
        }
        const int sLo = max(0, ib - WIN);
        const int sHi = min(HW - 1, ib + WIN + 3);
        float bs[4] = {b0, b1, b2, b3};
        #pragma unroll
        for (int w = 0; w < 4; ++w) {
            const int i = ib + w;
            float D2 = (float)(i * i) + bs[w];
            // exact iff no missed candidate can beat D2:
            //   col-window misses: dist^2 >= 8^2 = 64
            //   row-window misses: dist^2 >= dl^2 / dr^2
            const int dl = i - sLo + 1, dr = sHi + 1 - i;
            const bool need = (D2 > 64.f) ||
                              ((sLo > 0) && (D2 > (float)(dl * dl))) ||
                              ((sHi < HW - 1) && (D2 > (float)(dr * dr)));
            if (need) {  // statistically-dead exact fallback (global scan)
                const int jg = j0 + jj;
                float bb = 1e6f - (float)jg;     // empty-row/empty-image floor
                bb = bb * bb;
                for (int k = 0; k < HW; ++k) {
                    const float rowt = (float)((i - k) * (i - k));
                    if (rowt >= bb) continue;
                    for (int d = 0; d < HW; ++d) {
                        const float dd = rowt + (float)(d * d);
                        if (dd >= bb) break;
                        if (edge_at(segc, k, jg - d) || edge_at(segc, k, jg + d)) {
                            bb = dd; break;
                        }
                    }
                }
                D2 = bb;
            }
            const unsigned wbit = (esb[i - i0] >> jj) & 1u;
            lsum += wbit ? sqrtf(D2) : 0.f;
        }
    }

    // reduce: wave shuffle then cross-wave via LDS; ONE plain store per block
    #pragma unroll
    for (int off = 32; off > 0; off >>= 1) lsum += __shfl_down(lsum, off);
    if ((t & 63) == 0) wsum[t >> 6] = lsum;
    __syncthreads();
    if (t == 0) {
        const int bid = blockIdx.x + 64 * (blockIdx.y + 16 * blockIdx.z);
        partial[bid] = wsum[0] + wsum[1] + wsum[2] + wsum[3];
    }
}

// ---------------- Kernel C: reduce 2048 partials + sigmoid ----------------
__global__ __launch_bounds__(256)
void k_fin(const float* __restrict__ partial, float* __restrict__ out)
{
    const int t = threadIdx.x;
    float s = 0.f;
    #pragma unroll
    for (int q = 0; q < 8; ++q) s += partial[t + q * 256];
    #pragma unroll
    for (int off = 32; off > 0; off >>= 1) s += __shfl_down(s, off);
    __shared__ float w[4];
    if ((t & 63) == 0) w[t >> 6] = s;
    __syncthreads();
    if (t == 0) {
        const float tot = w[0] + w[1] + w[2] + w[3];
        const float loss = tot * (1.f / (2.f * 1024.f * 1024.f));
        out[0] = 1.f / (1.f + expf(-loss));
    }
}

extern "C" void kernel_launch(void* const* d_in, const int* in_sizes, int n_in,
                              void* d_out, int out_size, void* d_ws, size_t ws_size,
                              hipStream_t stream)
{
    const float* preds   = (const float*)d_in[0];
    const float* targets = (const float*)d_in[1];
    float* out = (float*)d_out;

    float* partial = (float*)d_ws;   // 8 KB

    dim3 gM(HW / 16, HW / RPB, 2);   // 64 x 16 x 2 = 2048 blocks
    k_main<<<gM, 256, 0, stream>>>(preds, targets, partial);

    k_fin<<<1, 256, 0, stream>>>(partial, out);
}

// Round 15
// 69.415 us; speedup vs baseline: 1.0425x; 1.0425x over previous
//
#include <hip/hip_runtime.h>
#include <math.h>

// BoundaryDistanceLoss — H=W=1024 binary masks (float 0/1).
// edges = seg - erode3x3(seg); exact EDT of edges; loss =
// sigmoid((mean(target_edges*pred_dt) + mean(pred_edges*target_dt))/2).
//
// R14->R15: XCD-aware task swizzle. R14 was neutral -> k_main is FETCH-bound:
// R10 profile showed 50MB HBM fetch vs ~9MB unique (8 private XCD L2s each
// refetching cache-cold rows; poison fill evicts everything). Now 1D grid,
// task derived so all blocks with bid%8==x cover ONE row band (both images,
// all col tiles): per-XCD footprint ~1.2MB, total ~10MB. Math identical to
// R13/R14 (absmax 0.0). 2 nodes, no atomics/fences.
//
// ws layout: partial (8KB f32) only.

#define HW 1024
#define WIN 8
#define RPB 64
#define KROWS (RPB + 2 * WIN)   // 80
#define HS_STRIDE 17
#define NC (RPB + 18)           // 82 segc rows: [i0-9, i0+73)
#define NW (RPB + 2)            // 66 segw rows: [i0-1, i0+65)
#define NROWS (NC + NW)         // 148
#define NSLOT (NROWS * 8)       // 1184 lane-slots (8 chunks/row)

// edge test straight from global seg (fallback only; zero-pad semantics)
__device__ inline int edge_at(const float* __restrict__ seg, int k, int j)
{
    if ((unsigned)k >= (unsigned)HW || (unsigned)j >= (unsigned)HW) return 0;
    if (seg[k * HW + j] == 0.f) return 0;
    bool all9 = true;
    #pragma unroll
    for (int dy = -1; dy <= 1; ++dy)
        #pragma unroll
        for (int dx = -1; dx <= 1; ++dx) {
            const int kk = k + dy, jj = j + dx;
            const float v = ((unsigned)kk < (unsigned)HW && (unsigned)jj < (unsigned)HW)
                            ? seg[kk * HW + jj] : 0.f;
            all9 = all9 && (v != 0.f);
        }
    return all9 ? 0 : 1;
}

// ------------- Fused kernel: windowed row-pass + column EDT + partial -------
// 1D grid of 2048 blocks, block 256. XCD-aware decode: bid%8 selects the
// row band (it = (bid&7)*2 + bit9), so each XCD's private L2 sees ~1.2MB.
__global__ __launch_bounds__(256)
void k_main(const float* __restrict__ pred, const float* __restrict__ targ,
            float* __restrict__ partial)
{
    const int t   = threadIdx.x;
    const int bid = blockIdx.x;               // 0..2047
    const int xcd = bid & 7;
    const int sub = bid >> 3;                 // 0..255
    const int jt  = sub & 63;                 // col tile 0..63
    const int r2  = sub >> 6;                 // 0..3
    const int mc  = r2 & 1;                   // image direction
    const int it  = xcd * 2 + (r2 >> 1);      // row chunk 0..15 (band per XCD)
    const int j0 = jt * 16;
    const int i0 = it * RPB;
    const float* __restrict__ segc = mc ? targ : pred;   // image whose DT we take
    const float* __restrict__ segw = mc ? pred : targ;   // OTHER image (weights)

    __shared__ unsigned s_m[NROWS];          // u32 row masks (segc then segw)
    __shared__ float hs[KROWS * HS_STRIDE];
    __shared__ unsigned short esb[RPB];
    __shared__ float wsum[4];

    // 32-col window: cols [W0, W0+32); tile at bits 8..23.
    // W0 = 16*jt - 8 is a multiple of 4 -> float4 chunks 16B-aligned and
    // never straddle the image border.
    const int W0 = j0 - 8;

    // Phase 1: stage window bits — 8 lanes per row, coalesced float4 loads,
    // in-register nibble, 3-step shfl_xor OR combine, lane0-of-8 stores mask.
    #pragma unroll
    for (int itr = 0; itr < 5; ++itr) {
        const int idx = t + itr * 256;
        unsigned partm = 0;
        int row = -1;
        if (idx < NSLOT) {
            row = idx >> 3;
            const int c4 = idx & 7;
            const int isW = row >= NC;
            const int gr  = isW ? (i0 - 1 + (row - NC)) : (i0 - 9 + row);
            const int c   = W0 + c4 * 4;
            float4 v = make_float4(0.f, 0.f, 0.f, 0.f);
            if ((unsigned)gr < (unsigned)HW && (unsigned)c <= 1020u) {
                const float* __restrict__ base = isW ? segw : segc;
                v = *(const float4*)&base[gr * HW + c];
            }
            const unsigned by = (unsigned)(v.x != 0.f) | ((unsigned)(v.y != 0.f) << 1)
                              | ((unsigned)(v.z != 0.f) << 2) | ((unsigned)(v.w != 0.f) << 3);
            partm = by << (4 * c4);
        }
        partm |= __shfl_xor(partm, 1);
        partm |= __shfl_xor(partm, 2);
        partm |= __shfl_xor(partm, 4);
        if (idx < NSLOT && (t & 7) == 0) s_m[row] = partm;
    }
    __syncthreads();

    // Phase 2a: weight edge words (other image), rows [i0, i0+64)
    if (t < RPB) {
        const unsigned sA = s_m[NC + t], sB = s_m[NC + t + 1], sC = s_m[NC + t + 2];
        const unsigned va = sA & sB & sC;
        const unsigned er = va & (va << 1) & (va >> 1);
        const unsigned edge = sB & ~er;          // tile bits 8..23 have valid nbrs
        esb[t] = (unsigned short)((edge >> 8) & 0xFFFFu);
    }
    // Phase 2b: windowed row-pass -> h = g^2 + kr^2 (threads 0..79, u32 ops)
    if (t < KROWS) {
        const int kr = i0 - WIN + t;             // edge row for hs row t
        float* __restrict__ hrow = &hs[t * HS_STRIDE];
        if ((unsigned)kr < (unsigned)HW) {
            const unsigned sA = s_m[t], sB = s_m[t + 1], sC = s_m[t + 2];
            const unsigned va = sA & sB & sC;
            const unsigned er = va & (va << 1) & (va >> 1);
            // bits 0/31 lack a col-neighbor: excluded as edge candidates; any
            // such miss is >=8 cols from the tile -> covered by the 64 check
            const unsigned edge = (sB & ~er) & 0x7FFFFFFEu;
            const float krk = (float)(kr * kr);
            #pragma unroll
            for (int jc = 0; jc < 16; ++jc) {
                const int p = 8 + jc;            // p in [8,24)
                const unsigned mle = edge & ((1u << (p + 1)) - 1u);
                const unsigned mge = edge >> p;
                int g = 1 << 20;
                if (mle) g = p - (31 - __clz(mle));
                if (mge) g = min(g, __ffs(mge) - 1);
                hrow[jc] = (g < (1 << 20)) ? fmaf((float)g, (float)g, krk) : 1e30f;
            }
        } else {
            #pragma unroll
            for (int jc = 0; jc < 16; ++jc) hrow[jc] = 1e30f;
        }
    }
    __syncthreads();

    // Phase 3: column EDT (windowed, exact) + weighted sum
    const int jj = t & 15;
    const int iw = t >> 4;                       // 0..15, each owns 4 rows
    float lsum = 0.f;
    {
        const int ib = i0 + iw * 4;              // 4 consecutive output rows
        const int kkS = iw * 4;                  // = (ib-WIN) - (i0-WIN)
        float b0 = 3e38f, b1 = 3e38f, b2 = 3e38f, b3 = 3e38f;
        float kf = (float)(ib - WIN);
        const float m0 = -2.f * (float)(ib);
        const float m1 = -2.f * (float)(ib + 1);
        const float m2 = -2.f * (float)(ib + 2);
        const float m3 = -2.f * (float)(ib + 3);
        #pragma unroll
        for (int kk = kkS; kk < kkS + 2 * WIN + 4; ++kk) {
            const float hvv = hs[kk * HS_STRIDE + jj];
            b0 = fminf(b0, fmaf(m0, kf, hvv));
            b1 = fminf(b1, fmaf(m1, kf, hvv));
            b2 = fminf(b2, fmaf(m2, kf, hvv));
            b3 = fminf(b3, fmaf(m3, kf, hvv));
            kf += 1.f;
        }
        const int sLo = max(0, ib - WIN);
        const int sHi = min(HW - 1, ib + WIN + 3);
        float bs[4] = {b0, b1, b2, b3};
        #pragma unroll
        for (int w = 0; w < 4; ++w) {
            const int i = ib + w;
            float D2 = (float)(i * i) + bs[w];
            // exact iff no missed candidate can beat D2:
            //   col-window misses: dist^2 >= 8^2 = 64
            //   row-window misses: dist^2 >= dl^2 / dr^2
            const int dl = i - sLo + 1, dr = sHi + 1 - i;
            const bool need = (D2 > 64.f) ||
                              ((sLo > 0) && (D2 > (float)(dl * dl))) ||
                              ((sHi < HW - 1) && (D2 > (float)(dr * dr)));
            if (need) {  // statistically-dead exact fallback (global scan)
                const int jg = j0 + jj;
                float bb = 1e6f - (float)jg;     // empty-row/empty-image floor
                bb = bb * bb;
                for (int k = 0; k < HW; ++k) {
                    const float rowt = (float)((i - k) * (i - k));
                    if (rowt >= bb) continue;
                    for (int d = 0; d < HW; ++d) {
                        const float dd = rowt + (float)(d * d);
                        if (dd >= bb) break;
                        if (edge_at(segc, k, jg - d) || edge_at(segc, k, jg + d)) {
                            bb = dd; break;
                        }
                    }
                }
                D2 = bb;
            }
            const unsigned wbit = (esb[i - i0] >> jj) & 1u;
            lsum += wbit ? sqrtf(D2) : 0.f;
        }
    }

    // reduce: wave shuffle then cross-wave via LDS; ONE plain store per block
    #pragma unroll
    for (int off = 32; off > 0; off >>= 1) lsum += __shfl_down(lsum, off);
    if ((t & 63) == 0) wsum[t >> 6] = lsum;
    __syncthreads();
    if (t == 0)
        partial[bid] = wsum[0] + wsum[1] + wsum[2] + wsum[3];
}

// ---------------- Kernel C: reduce 2048 partials + sigmoid ----------------
__global__ __launch_bounds__(256)
void k_fin(const float* __restrict__ partial, float* __restrict__ out)
{
    const int t = threadIdx.x;
    float s = 0.f;
    #pragma unroll
    for (int q = 0; q < 8; ++q) s += partial[t + q * 256];
    #pragma unroll
    for (int off = 32; off > 0; off >>= 1) s += __shfl_down(s, off);
    __shared__ float w[4];
    if ((t & 63) == 0) w[t >> 6] = s;
    __syncthreads();
    if (t == 0) {
        const float tot = w[0] + w[1] + w[2] + w[3];
        const float loss = tot * (1.f / (2.f * 1024.f * 1024.f));
        out[0] = 1.f / (1.f + expf(-loss));
    }
}

extern "C" void kernel_launch(void* const* d_in, const int* in_sizes, int n_in,
                              void* d_out, int out_size, void* d_ws, size_t ws_size,
                              hipStream_t stream)
{
    const float* preds   = (const float*)d_in[0];
    const float* targets = (const float*)d_in[1];
    float* out = (float*)d_out;

    float* partial = (float*)d_ws;   // 8 KB

    k_main<<<dim3(2048), 256, 0, stream>>>(preds, targets, partial);
    k_fin<<<1, 256, 0, stream>>>(partial, out);
}